// Round 8
// baseline (306.792 us; speedup 1.0000x reference)
//
#include <hip/hip_runtime.h>
#include <math.h>

#define BATCH 2
#define SEQ   2048
#define HID   1024
#define NHEAD 16
#define ROWS  (BATCH*SEQ)   // 4096
#define QKV_N (3*HID)       // 3072

// Q pre-scaled by 1/sqrt(64) * log2(e): attention works in exp2 domain.
#define Q_SCALE 0.18033688011112042f

typedef __attribute__((ext_vector_type(8))) short bf16x8;   // 8 bf16 in 4 VGPRs
typedef __attribute__((ext_vector_type(4))) float f32x4;

__device__ __forceinline__ unsigned short f2b(float f) {
    unsigned u = __float_as_uint(f);
    u += 0x7FFF + ((u >> 16) & 1);          // round-to-nearest-even
    return (unsigned short)(u >> 16);
}
// pack two f32 -> one u32 of 2 bf16 (lo = a, hi = b), known-good rounding
__device__ __forceinline__ unsigned pk2(float a, float b) {
    return (unsigned)f2b(a) | ((unsigned)f2b(b) << 16);
}

// global -> LDS direct copy, 16B per lane; LDS dest is wave-uniform base + lane*16
#define GLOAD_LDS16(gp, lp) \
    __builtin_amdgcn_global_load_lds((const __attribute__((address_space(1))) void*)(gp), \
                                     (__attribute__((address_space(3))) void*)(lp), 16, 0, 0)

// fused f32->bf16 conversion for the three input tensors
__global__ __launch_bounds__(256)
void cvt_all(const float* __restrict__ a, unsigned short* __restrict__ oa, int na4,
             const float* __restrict__ b, unsigned short* __restrict__ ob, int nb4,
             const float* __restrict__ c, unsigned short* __restrict__ oc, int nc4) {
    int i = blockIdx.x * 256 + threadIdx.x;
    const float* src; unsigned short* dst; int j;
    if (i < na4)            { src = a; dst = oa; j = i; }
    else if (i < na4 + nb4) { src = b; dst = ob; j = i - na4; }
    else if (i < na4 + nb4 + nc4) { src = c; dst = oc; j = i - na4 - nb4; }
    else return;
    float4 v = reinterpret_cast<const float4*>(src)[j];
    ushort4 o;
    o.x = f2b(v.x); o.y = f2b(v.y); o.z = f2b(v.z); o.w = f2b(v.w);
    reinterpret_cast<ushort4*>(dst)[j] = o;
}

// ---- C[M,N] = A[M,K] * B[N,K]^T + bias, bf16 inputs, fp32 accum --------------
// MODE 0: f32 output to Cout[M*N]
// MODE 2: qkv mode: cols <1024 (Q) -> bf16 pre-scaled by Q_SCALE; 1024..2047 (K)
//         -> bf16; both row-major [4096][3072]. cols >=2048 (V) -> bf16 V^T at
//         vt[(bh*64+d)*2048 + s]
template<int MODE>
__global__ __launch_bounds__(256)
void gemm_mfma(const unsigned short* __restrict__ A, const unsigned short* __restrict__ B,
               const float* __restrict__ bias, void* __restrict__ Cout,
               unsigned short* __restrict__ vt, int M, int N, int K) {
    __shared__ __align__(16) unsigned short As[128 * 32];   // 64B rows, swz(row&3)
    __shared__ __align__(16) unsigned short Bs[128 * 32];
    const int tid = threadIdx.x;
    const int w = tid >> 6, l = tid & 63;
    const int wm = w >> 1, wn = w & 1;
    const int l15 = l & 15, l4 = l >> 4;
    const long row0 = (long)blockIdx.y * 128;
    const long col0 = (long)blockIdx.x * 128;

    f32x4 acc[4][4];
    #pragma unroll
    for (int m = 0; m < 4; ++m)
        #pragma unroll
        for (int n = 0; n < 4; ++n) acc[m][n] = (f32x4)0.0f;

    const int lr   = l >> 2;                 // staging row within 16
    const int slot = (l & 3) ^ (lr & 3);     // pre-swizzled source granule

    for (int k0 = 0; k0 < K; k0 += 32) {
        __syncthreads();
        #pragma unroll
        for (int c = 0; c < 2; ++c) {
            int r = w * 32 + c * 16 + lr;
            GLOAD_LDS16(A + (row0 + r) * K + k0 + slot * 8, As + (w * 32 + c * 16) * 32);
            GLOAD_LDS16(B + (col0 + r) * K + k0 + slot * 8, Bs + (w * 32 + c * 16) * 32);
        }
        __syncthreads();

        bf16x8 af[4], bfr[4];
        #pragma unroll
        for (int m = 0; m < 4; ++m) {
            int row = wm * 64 + m * 16 + l15;
            af[m] = *(const bf16x8*)((const char*)As + row * 64 + ((l4 ^ (row & 3)) << 4));
        }
        #pragma unroll
        for (int n = 0; n < 4; ++n) {
            int row = wn * 64 + n * 16 + l15;
            bfr[n] = *(const bf16x8*)((const char*)Bs + row * 64 + ((l4 ^ (row & 3)) << 4));
        }
        #pragma unroll
        for (int m = 0; m < 4; ++m)
            #pragma unroll
            for (int n = 0; n < 4; ++n)
                acc[m][n] = __builtin_amdgcn_mfma_f32_16x16x32_bf16(af[m], bfr[n], acc[m][n], 0, 0, 0);
    }

    #pragma unroll
    for (int m = 0; m < 4; ++m) {
        #pragma unroll
        for (int n = 0; n < 4; ++n) {
            long ccol = col0 + wn * 64 + n * 16 + l15;
            float bv = bias[ccol];
            #pragma unroll
            for (int r2 = 0; r2 < 4; ++r2) {
                long crow = row0 + wm * 64 + m * 16 + l4 * 4 + r2;
                float v = acc[m][n][r2] + bv;
                if (MODE == 0) {
                    ((float*)Cout)[crow * N + ccol] = v;
                } else {
                    if (ccol < 1024) {
                        ((unsigned short*)Cout)[crow * QKV_N + ccol] = f2b(v * Q_SCALE);
                    } else if (ccol < 2048) {
                        ((unsigned short*)Cout)[crow * QKV_N + ccol] = f2b(v);
                    } else {
                        long cc = ccol - 2048;
                        long h = cc >> 6, d = cc & 63;
                        long b = crow >> 11, s = crow & 2047;
                        vt[(((b * NHEAD + h) * 64 + d) << 11) + s] = f2b(v);
                    }
                }
            }
        }
    }
}

// ---- flash attention, bf16 MFMA, barrier-free, K/V direct from L2 ------------
// 4 waves x 16 q-rows = 64 q-rows/block; grid 1024 -> 4 blocks/CU; waves fully
// independent (no __syncthreads). K/V MFMA fragments load straight from global
// (L2-resident: 2 MB per XCD with the swizzle); only the per-wave P tile uses LDS.
// qkv: [4096][3072] bf16 (Q prescaled, K at +1024); vt: [32][64][2048] bf16;
// attno: [4096][1024] bf16.
__global__ __launch_bounds__(256, 4)
void attn_mfma(const unsigned short* __restrict__ qkv, const unsigned short* __restrict__ vt,
               unsigned short* __restrict__ attno, const int* __restrict__ use_mask) {
    __shared__ __align__(16) unsigned short Ps[4][16 * 64]; // per-wave P [q][k], swz(row&7)
    const int tid = threadIdx.x;
    const int w = tid >> 6, l = tid & 63;
    const int l15 = l & 15, l4 = l >> 4;
    // XCD swizzle: 1024 blocks = 8 XCDs x 128; each XCD owns 4 consecutive bh
    const int bid  = blockIdx.x;
    const int orig = (bid & 7) * 128 + (bid >> 3);
    const int qt = orig & 31, bh = orig >> 5;
    const int b = bh >> 4, h = bh & 15;
    const int q0 = qt * 64;                   // block q-range [q0, q0+64)
    const int wq0 = q0 + w * 16;              // this wave's q-range [wq0, wq0+16)
    const int causal = use_mask[0];
    const int NT = causal ? (qt + 1) : (SEQ / 64);

    // Q fragments (B-operand of swapped QK^T): q-col = l15, k-slice ks*32+l4*8
    bf16x8 qf[2];
    {
        const unsigned short* qp = qkv + (size_t)(b * SEQ + wq0 + l15) * QKV_N + h * 64;
        qf[0] = *(const bf16x8*)(qp + l4 * 8);
        qf[1] = *(const bf16x8*)(qp + 32 + l4 * 8);
    }

    f32x4 o_acc[4];
    #pragma unroll
    for (int n = 0; n < 4; ++n) o_acc[n] = (f32x4)0.0f;
    f32x4 l_acc = (f32x4)0.0f;                // row sums via ones-MFMA

    // all-ones bf16 fragment for the row-sum MFMA (B layout-independent)
    bf16x8 ones;
    #pragma unroll
    for (int j = 0; j < 8; ++j) ones[j] = (short)0x3F80;

    unsigned short* pw = Ps[w];

    // per-lane walking pointers for direct fragment loads (element units)
    // K fragment (A-op): K[kk0 + n*16 + l15][ks*32 + l4*8 + j]
    const unsigned short* kq = qkv + (size_t)b * SEQ * QKV_N + HID + h * 64
                                   + (size_t)l15 * QKV_N + l4 * 8;
    // V fragment (B-op): V^T[n*16 + l15][kk0 + ks*32 + l4*8 + j]
    const unsigned short* vq = vt + (size_t)bh * 64 * SEQ + (size_t)l15 * SEQ + l4 * 8;

    for (int kt = 0; kt < NT; ++kt) {
        // K fragments for this tile, straight from L2
        bf16x8 kf[2][4];
        #pragma unroll
        for (int ks = 0; ks < 2; ++ks)
            #pragma unroll
            for (int n = 0; n < 4; ++n)
                kf[ks][n] = *(const bf16x8*)(kq + (size_t)n * 16 * QKV_N + ks * 32);

        // S^T = K Q^T: s_acc[n]: k-row = kt*64+n*16+l4*4+r2, q-col = wq0+l15
        f32x4 s_acc[4];
        #pragma unroll
        for (int n = 0; n < 4; ++n) s_acc[n] = (f32x4)0.0f;
        __builtin_amdgcn_s_setprio(1);
        #pragma unroll
        for (int ks = 0; ks < 2; ++ks)
            #pragma unroll
            for (int n = 0; n < 4; ++n)
                s_acc[n] = __builtin_amdgcn_mfma_f32_16x16x32_bf16(kf[ks][n], qf[ks], s_acc[n], 0, 0, 0);
        __builtin_amdgcn_s_setprio(0);

        // V fragments: issue now so L2 latency hides under the softmax below
        bf16x8 vf[2][4];
        #pragma unroll
        for (int ks = 0; ks < 2; ++ks)
            #pragma unroll
            for (int n = 0; n < 4; ++n)
                vf[ks][n] = *(const bf16x8*)(vq + (size_t)n * 16 * SEQ + ks * 32);

        if (causal) {
            int kk0 = kt * 64;
            #pragma unroll
            for (int n = 0; n < 4; ++n)
                #pragma unroll
                for (int r2 = 0; r2 < 4; ++r2) {
                    int krow = kk0 + n * 16 + l4 * 4 + r2;
                    int qcol = wq0 + l15;
                    if (krow > qcol) s_acc[n][r2] = -INFINITY;
                }
        }

        // P = exp2(S) raw (no shift: exact up to normalization), pack pairs,
        // write b64 to per-wave P [q=l15][k]
        #pragma unroll
        for (int n = 0; n < 4; ++n) {
            float p0 = exp2f(s_acc[n][0]);
            float p1 = exp2f(s_acc[n][1]);
            float p2 = exp2f(s_acc[n][2]);
            float p3 = exp2f(s_acc[n][3]);
            uint2 pk;
            pk.x = pk2(p0, p1);
            pk.y = pk2(p2, p3);
            int byteoff = (n * 32 + l4 * 8) ^ ((l15 & 7) << 4);
            *(uint2*)((char*)pw + l15 * 128 + byteoff) = pk;
        }

        // O += P V; row sums via ones-MFMA (P written+read by same wave, no barrier)
        __builtin_amdgcn_s_setprio(1);
        #pragma unroll
        for (int ks = 0; ks < 2; ++ks) {
            bf16x8 pf = *(const bf16x8*)((const char*)pw + l15 * 128 + (((ks * 4 + l4) ^ (l15 & 7)) << 4));
            l_acc = __builtin_amdgcn_mfma_f32_16x16x32_bf16(pf, ones, l_acc, 0, 0, 0);
            #pragma unroll
            for (int n = 0; n < 4; ++n)
                o_acc[n] = __builtin_amdgcn_mfma_f32_16x16x32_bf16(pf, vf[ks][n], o_acc[n], 0, 0, 0);
        }
        __builtin_amdgcn_s_setprio(0);

        kq += (size_t)64 * QKV_N;             // K advances 64 tokens
        vq += 64;                             // V^T advances 64 columns
    }

    // epilogue: l_acc[r2] is the row sum for q = wq0 + l4*4 + r2 —
    // exactly o_acc's row layout, no shuffles needed
    #pragma unroll
    for (int r2 = 0; r2 < 4; ++r2) {
        float inv = 1.0f / l_acc[r2];
        size_t orow = (size_t)(b * SEQ + wq0 + l4 * 4 + r2);
        #pragma unroll
        for (int n = 0; n < 4; ++n)
            attno[orow * HID + h * 64 + n * 16 + l15] = f2b(o_acc[n][r2] * inv);
    }
}

extern "C" void kernel_launch(void* const* d_in, const int* in_sizes, int n_in,
                              void* d_out, int out_size, void* d_ws, size_t ws_size,
                              hipStream_t stream) {
    const float* features = (const float*)d_in[0];
    const float* qkv_w    = (const float*)d_in[1];
    const float* qkv_b    = (const float*)d_in[2];
    const float* out_w    = (const float*)d_in[3];
    const float* out_b    = (const float*)d_in[4];
    const int*   use_mask = (const int*)d_in[5];

    char* ws = (char*)d_ws;
    unsigned short* fbf     = (unsigned short*)(ws);              // 8 MB  features bf16
    unsigned short* wbf     = (unsigned short*)(ws + 8388608);    // 6 MB  qkv_w bf16
    unsigned short* owbf    = (unsigned short*)(ws + 14680064);   // 2 MB  out_w bf16
    unsigned short* qkvbf   = (unsigned short*)(ws + 16777216);   // 24 MB qkv bf16 (Q,K used)
    unsigned short* vtbuf   = (unsigned short*)(ws + 41943040);   // 8 MB  V^T bf16
    unsigned short* attnobf = (unsigned short*)(ws + 50331648);   // 8 MB  attn out bf16

    cvt_all<<<8192, 256, 0, stream>>>(features, fbf, 1048576,
                                      qkv_w, wbf, 786432,
                                      out_w, owbf, 262144);

    dim3 g1(QKV_N / 128, ROWS / 128);   // (24, 32)
    gemm_mfma<2><<<g1, 256, 0, stream>>>(fbf, wbf, qkv_b, (void*)qkvbf, vtbuf,
                                         ROWS, QKV_N, HID);

    attn_mfma<<<1024, 256, 0, stream>>>(qkvbf, vtbuf, attnobf, use_mask);

    dim3 g3(HID / 128, ROWS / 128);     // (8, 32)
    gemm_mfma<0><<<g3, 256, 0, stream>>>(attnobf, owbf, out_b, d_out, (unsigned short*)nullptr,
                                         ROWS, HID, HID);
}

// Round 9
// 148.361 us; speedup vs baseline: 2.0679x; 2.0679x over previous
//
#include <hip/hip_runtime.h>
#include <hip/hip_bf16.h>
#include <math.h>

#define BATCH 2
#define SEQ   2048
#define HID   1024
#define NHEAD 16
#define ROWS  (BATCH*SEQ)   // 4096
#define QKV_N (3*HID)       // 3072

// Q pre-scaled by 1/sqrt(64) * log2(e): attention works in exp2 domain.
#define Q_SCALE 0.18033688011112042f

typedef __attribute__((ext_vector_type(8))) short bf16x8;   // 8 bf16 in 4 VGPRs
typedef __attribute__((ext_vector_type(4))) float f32x4;

__device__ __forceinline__ unsigned short f2b(float f) {
    unsigned u = __float_as_uint(f);
    u += 0x7FFF + ((u >> 16) & 1);          // round-to-nearest-even
    return (unsigned short)(u >> 16);
}
// pack two f32 -> u32 of 2 bf16 (lo=a, hi=b) via compiler (emits v_cvt_pk_bf16_f32)
__device__ __forceinline__ unsigned pk2c(float a, float b) {
    __hip_bfloat162 h = __float22bfloat162_rn(float2{a, b});
    union { __hip_bfloat162 h2; unsigned u; } cv; cv.h2 = h;
    return cv.u;
}

// global -> LDS direct copy, 16B per lane; LDS dest is wave-uniform base + lane*16
#define GLOAD_LDS16(gp, lp) \
    __builtin_amdgcn_global_load_lds((const __attribute__((address_space(1))) void*)(gp), \
                                     (__attribute__((address_space(3))) void*)(lp), 16, 0, 0)

// fused f32->bf16 conversion for the three input tensors
__global__ __launch_bounds__(256)
void cvt_all(const float* __restrict__ a, unsigned short* __restrict__ oa, int na4,
             const float* __restrict__ b, unsigned short* __restrict__ ob, int nb4,
             const float* __restrict__ c, unsigned short* __restrict__ oc, int nc4) {
    int i = blockIdx.x * 256 + threadIdx.x;
    const float* src; unsigned short* dst; int j;
    if (i < na4)            { src = a; dst = oa; j = i; }
    else if (i < na4 + nb4) { src = b; dst = ob; j = i - na4; }
    else if (i < na4 + nb4 + nc4) { src = c; dst = oc; j = i - na4 - nb4; }
    else return;
    float4 v = reinterpret_cast<const float4*>(src)[j];
    ushort4 o;
    o.x = f2b(v.x); o.y = f2b(v.y); o.z = f2b(v.z); o.w = f2b(v.w);
    reinterpret_cast<ushort4*>(dst)[j] = o;
}

// ---- C[M,N] = A[M,K] * B[N,K]^T + bias, bf16 inputs, fp32 accum --------------
// MODE 0: f32 output to Cout[M*N]
// MODE 2: qkv mode: cols <1024 (Q) -> bf16 pre-scaled by Q_SCALE; 1024..2047 (K)
//         -> bf16; both row-major [4096][3072]. cols >=2048 (V) -> bf16 V^T at
//         vt[(bh*64+d)*2048 + s]
template<int MODE>
__global__ __launch_bounds__(256)
void gemm_mfma(const unsigned short* __restrict__ A, const unsigned short* __restrict__ B,
               const float* __restrict__ bias, void* __restrict__ Cout,
               unsigned short* __restrict__ vt, int M, int N, int K) {
    __shared__ __align__(16) unsigned short As[128 * 32];   // 64B rows, swz(row&3)
    __shared__ __align__(16) unsigned short Bs[128 * 32];
    const int tid = threadIdx.x;
    const int w = tid >> 6, l = tid & 63;
    const int wm = w >> 1, wn = w & 1;
    const int l15 = l & 15, l4 = l >> 4;
    const long row0 = (long)blockIdx.y * 128;
    const long col0 = (long)blockIdx.x * 128;

    f32x4 acc[4][4];
    #pragma unroll
    for (int m = 0; m < 4; ++m)
        #pragma unroll
        for (int n = 0; n < 4; ++n) acc[m][n] = (f32x4)0.0f;

    const int lr   = l >> 2;                 // staging row within 16
    const int slot = (l & 3) ^ (lr & 3);     // pre-swizzled source granule

    for (int k0 = 0; k0 < K; k0 += 32) {
        __syncthreads();
        #pragma unroll
        for (int c = 0; c < 2; ++c) {
            int r = w * 32 + c * 16 + lr;
            GLOAD_LDS16(A + (row0 + r) * K + k0 + slot * 8, As + (w * 32 + c * 16) * 32);
            GLOAD_LDS16(B + (col0 + r) * K + k0 + slot * 8, Bs + (w * 32 + c * 16) * 32);
        }
        __syncthreads();

        bf16x8 af[4], bfr[4];
        #pragma unroll
        for (int m = 0; m < 4; ++m) {
            int row = wm * 64 + m * 16 + l15;
            af[m] = *(const bf16x8*)((const char*)As + row * 64 + ((l4 ^ (row & 3)) << 4));
        }
        #pragma unroll
        for (int n = 0; n < 4; ++n) {
            int row = wn * 64 + n * 16 + l15;
            bfr[n] = *(const bf16x8*)((const char*)Bs + row * 64 + ((l4 ^ (row & 3)) << 4));
        }
        #pragma unroll
        for (int m = 0; m < 4; ++m)
            #pragma unroll
            for (int n = 0; n < 4; ++n)
                acc[m][n] = __builtin_amdgcn_mfma_f32_16x16x32_bf16(af[m], bfr[n], acc[m][n], 0, 0, 0);
    }

    #pragma unroll
    for (int m = 0; m < 4; ++m) {
        #pragma unroll
        for (int n = 0; n < 4; ++n) {
            long ccol = col0 + wn * 64 + n * 16 + l15;
            float bv = bias[ccol];
            #pragma unroll
            for (int r2 = 0; r2 < 4; ++r2) {
                long crow = row0 + wm * 64 + m * 16 + l4 * 4 + r2;
                float v = acc[m][n][r2] + bv;
                if (MODE == 0) {
                    ((float*)Cout)[crow * N + ccol] = v;
                } else {
                    if (ccol < 1024) {
                        ((unsigned short*)Cout)[crow * QKV_N + ccol] = f2b(v * Q_SCALE);
                    } else if (ccol < 2048) {
                        ((unsigned short*)Cout)[crow * QKV_N + ccol] = f2b(v);
                    } else {
                        long cc = ccol - 2048;
                        long h = cc >> 6, d = cc & 63;
                        long b = crow >> 11, s = crow & 2047;
                        vt[(((b * NHEAD + h) * 64 + d) << 11) + s] = f2b(v);
                    }
                }
            }
        }
    }
}

// ---- flash attention, bf16 MFMA, k-split wave specialization -----------------
// Block = 4 waves over a 64-q-row tile: wave w owns q-half (w&1)*32 rows and
// k-half (w>>1)*32 of each 64-token K/V tile. Raw-exp2 softmax makes k-partials
// additive; one LDS merge per block at the end. Grid 1024 -> 4 blocks/CU.
// qkv: [4096][3072] bf16 (Q prescaled, K at +1024); vt: [32][64][2048] bf16;
// attno: [4096][1024] bf16.
__global__ __launch_bounds__(256, 4)
void attn_mfma(const unsigned short* __restrict__ qkv, const unsigned short* __restrict__ vt,
               unsigned short* __restrict__ attno, const int* __restrict__ use_mask) {
    __shared__ __align__(16) unsigned short Ks [64 * 64];   // [token][d], swz(row&7)
    __shared__ __align__(16) unsigned short Vts[64 * 64];   // [d][token], swz(row&7)
    __shared__ __align__(16) unsigned short Ps [4][32 * 32];// per-wave P [q][k], 64B rows swz(row&3)
    const int tid = threadIdx.x;
    const int w = tid >> 6, l = tid & 63;
    const int l15 = l & 15, l4 = l >> 4;
    // XCD swizzle: 1024 blocks = 8 XCDs x 128; each XCD owns 4 consecutive bh
    const int bid  = blockIdx.x;
    const int orig = (bid & 7) * 128 + (bid >> 3);
    const int qt = orig & 31, bh = orig >> 5;
    const int b = bh >> 4, h = bh & 15;
    const int q0 = qt * 64;                   // block q-range [q0, q0+64)
    const int qh = w & 1, kh = w >> 1;        // wave's q-half / k-half
    const int wq0 = q0 + qh * 32;             // wave q-range [wq0, wq0+32)
    const int causal = use_mask[0];
    const int NT = causal ? (qt + 1) : (SEQ / 64);

    // Q fragments (B-op of swapped QK^T): col q = wq0 + m*16 + l15, d-slice ks*32+l4*8
    bf16x8 qf[2][2];
    #pragma unroll
    for (int m = 0; m < 2; ++m) {
        const unsigned short* qp = qkv + (size_t)(b * SEQ + wq0 + m * 16 + l15) * QKV_N + h * 64;
        qf[m][0] = *(const bf16x8*)(qp + l4 * 8);
        qf[m][1] = *(const bf16x8*)(qp + 32 + l4 * 8);
    }

    f32x4 o_acc[2][4];
    #pragma unroll
    for (int m = 0; m < 2; ++m)
        #pragma unroll
        for (int n = 0; n < 4; ++n) o_acc[m][n] = (f32x4)0.0f;
    f32x4 l_acc[2] = {(f32x4)0.0f, (f32x4)0.0f};   // partial row sums (ones-MFMA)

    bf16x8 ones;
    #pragma unroll
    for (int j = 0; j < 8; ++j) ones[j] = (short)0x3F80;

    const int srow = l >> 3, g = l & 7;
    const int r0   = w * 16 + srow;           // rows staged by this thread (and +8)
    const int wso  = (g ^ srow) << 3;         // swizzled granule offset (ushorts)
    unsigned short* pw = Ps[w];

    // walking source pointers (hoisted 64-bit address math)
    const unsigned short* kp = qkv + (size_t)b * SEQ * QKV_N + HID + h * 64
                                   + (size_t)r0 * QKV_N + g * 8;
    const unsigned short* vp = vt + (size_t)bh * 64 * SEQ + (size_t)r0 * SEQ + g * 8;

    // prologue: prefetch tile 0 into registers (T14)
    bf16x8 kreg[2], vreg[2];
    kreg[0] = *(const bf16x8*)(kp);
    kreg[1] = *(const bf16x8*)(kp + 8 * QKV_N);
    vreg[0] = *(const bf16x8*)(vp);
    vreg[1] = *(const bf16x8*)(vp + 8 * SEQ);
    kp += (size_t)64 * QKV_N;
    vp += 64;

    for (int kt = 0; kt < NT; ++kt) {
        __syncthreads();   // previous tile's LDS reads done
        #pragma unroll
        for (int c = 0; c < 2; ++c) {
            *(bf16x8*)(Ks  + (r0 + c * 8) * 64 + wso) = kreg[c];
            *(bf16x8*)(Vts + (r0 + c * 8) * 64 + wso) = vreg[c];
        }
        __syncthreads();   // tile staged

        // issue next tile's global loads; latency hides under compute below
        if (kt + 1 < NT) {
            kreg[0] = *(const bf16x8*)(kp);
            kreg[1] = *(const bf16x8*)(kp + 8 * QKV_N);
            vreg[0] = *(const bf16x8*)(vp);
            vreg[1] = *(const bf16x8*)(vp + 8 * SEQ);
            kp += (size_t)64 * QKV_N;
            vp += 64;
        }

        // S^T = K Q^T over the wave's 32x32 patch:
        // s_acc[n2][m]: k-row = kt*64 + kh*32 + n2*16 + l4*4 + r2, q-col = wq0 + m*16 + l15
        f32x4 s_acc[2][2];
        #pragma unroll
        for (int n2 = 0; n2 < 2; ++n2)
            #pragma unroll
            for (int m = 0; m < 2; ++m) s_acc[n2][m] = (f32x4)0.0f;
        __builtin_amdgcn_s_setprio(1);
        #pragma unroll
        for (int ks = 0; ks < 2; ++ks) {
            #pragma unroll
            for (int n2 = 0; n2 < 2; ++n2) {
                int row = kh * 32 + n2 * 16 + l15;
                bf16x8 kf = *(const bf16x8*)((const char*)Ks + row * 128 + (((ks * 4 + l4) ^ (row & 7)) << 4));
                #pragma unroll
                for (int m = 0; m < 2; ++m)
                    s_acc[n2][m] = __builtin_amdgcn_mfma_f32_16x16x32_bf16(kf, qf[m][ks], s_acc[n2][m], 0, 0, 0);
            }
        }
        __builtin_amdgcn_s_setprio(0);

        if (causal) {
            int kk0 = kt * 64 + kh * 32;
            #pragma unroll
            for (int n2 = 0; n2 < 2; ++n2)
                #pragma unroll
                for (int m = 0; m < 2; ++m)
                    #pragma unroll
                    for (int r2 = 0; r2 < 4; ++r2) {
                        int krow = kk0 + n2 * 16 + l4 * 4 + r2;
                        int qcol = wq0 + m * 16 + l15;
                        if (krow > qcol) s_acc[n2][m][r2] = -INFINITY;
                    }
        }

        // P = exp2(S) raw; pack pairs (compiler cvt_pk), write b64 to P [q][k] 32x32
        #pragma unroll
        for (int m = 0; m < 2; ++m) {
            int prow = m * 16 + l15;
            #pragma unroll
            for (int n2 = 0; n2 < 2; ++n2) {
                float p0 = exp2f(s_acc[n2][m][0]);
                float p1 = exp2f(s_acc[n2][m][1]);
                float p2 = exp2f(s_acc[n2][m][2]);
                float p3 = exp2f(s_acc[n2][m][3]);
                uint2 pk;
                pk.x = pk2c(p0, p1);
                pk.y = pk2c(p2, p3);
                int byteoff = (n2 * 32 + l4 * 8) ^ ((prow & 3) << 4);
                *(uint2*)((char*)pw + prow * 64 + byteoff) = pk;
            }
        }

        // O += P V over the wave's k-half (single K=32 chunk); l via ones-MFMA
        __builtin_amdgcn_s_setprio(1);
        bf16x8 pf[2];
        #pragma unroll
        for (int m = 0; m < 2; ++m) {
            int prow = m * 16 + l15;
            pf[m] = *(const bf16x8*)((const char*)pw + prow * 64 + ((l4 * 16) ^ ((prow & 3) << 4)));
            l_acc[m] = __builtin_amdgcn_mfma_f32_16x16x32_bf16(pf[m], ones, l_acc[m], 0, 0, 0);
        }
        #pragma unroll
        for (int n = 0; n < 4; ++n) {
            int vrow = n * 16 + l15;
            bf16x8 vf = *(const bf16x8*)((const char*)Vts + vrow * 128 + (((kh * 4 + l4) ^ (vrow & 7)) << 4));
            #pragma unroll
            for (int m = 0; m < 2; ++m)
                o_acc[m][n] = __builtin_amdgcn_mfma_f32_16x16x32_bf16(pf[m], vf, o_acc[m][n], 0, 0, 0);
        }
        __builtin_amdgcn_s_setprio(0);
    }

    // ---- cross-wave merge: (qh, kh=0) += (qh, kh=1); normalize; write --------
    __syncthreads();                           // all tiles' LDS reads done
    float* mq = (float*)(qh ? Vts : Ks);       // 32q x 64d f32 = 8KB per q-half
    float* lb = (float*)&Ps[0][0];             // 64 f32 row sums
    if (kh == 1) {
        #pragma unroll
        for (int m = 0; m < 2; ++m) {
            #pragma unroll
            for (int r2 = 0; r2 < 4; ++r2) {
                int qr = m * 16 + l4 * 4 + r2;
                #pragma unroll
                for (int n = 0; n < 4; ++n)
                    mq[qr * 64 + n * 16 + l15] = o_acc[m][n][r2];
                if (l15 == 0) lb[qh * 32 + qr] = l_acc[m][r2];
            }
        }
    }
    __syncthreads();
    if (kh == 0) {
        #pragma unroll
        for (int m = 0; m < 2; ++m) {
            #pragma unroll
            for (int r2 = 0; r2 < 4; ++r2) {
                int qr = m * 16 + l4 * 4 + r2;
                float lt = l_acc[m][r2] + lb[qh * 32 + qr];
                float inv = 1.0f / lt;
                size_t orow = (size_t)(b * SEQ + wq0 + qr);
                #pragma unroll
                for (int n = 0; n < 4; ++n) {
                    float o = o_acc[m][n][r2] + mq[qr * 64 + n * 16 + l15];
                    attno[orow * HID + h * 64 + n * 16 + l15] = f2b(o * inv);
                }
            }
        }
    }
}

extern "C" void kernel_launch(void* const* d_in, const int* in_sizes, int n_in,
                              void* d_out, int out_size, void* d_ws, size_t ws_size,
                              hipStream_t stream) {
    const float* features = (const float*)d_in[0];
    const float* qkv_w    = (const float*)d_in[1];
    const float* qkv_b    = (const float*)d_in[2];
    const float* out_w    = (const float*)d_in[3];
    const float* out_b    = (const float*)d_in[4];
    const int*   use_mask = (const int*)d_in[5];

    char* ws = (char*)d_ws;
    unsigned short* fbf     = (unsigned short*)(ws);              // 8 MB  features bf16
    unsigned short* wbf     = (unsigned short*)(ws + 8388608);    // 6 MB  qkv_w bf16
    unsigned short* owbf    = (unsigned short*)(ws + 14680064);   // 2 MB  out_w bf16
    unsigned short* qkvbf   = (unsigned short*)(ws + 16777216);   // 24 MB qkv bf16 (Q,K used)
    unsigned short* vtbuf   = (unsigned short*)(ws + 41943040);   // 8 MB  V^T bf16
    unsigned short* attnobf = (unsigned short*)(ws + 50331648);   // 8 MB  attn out bf16

    cvt_all<<<8192, 256, 0, stream>>>(features, fbf, 1048576,
                                      qkv_w, wbf, 786432,
                                      out_w, owbf, 262144);

    dim3 g1(QKV_N / 128, ROWS / 128);   // (24, 32)
    gemm_mfma<2><<<g1, 256, 0, stream>>>(fbf, wbf, qkv_b, (void*)qkvbf, vtbuf,
                                         ROWS, QKV_N, HID);

    attn_mfma<<<1024, 256, 0, stream>>>(qkvbf, vtbuf, attnobf, use_mask);

    dim3 g3(HID / 128, ROWS / 128);     // (8, 32)
    gemm_mfma<0><<<g3, 256, 0, stream>>>(attnobf, owbf, out_b, d_out, (unsigned short*)nullptr,
                                         ROWS, HID, HID);
}